// Round 1
// baseline (2800.994 us; speedup 1.0000x reference)
//
#include <hip/hip_runtime.h>
#include <math.h>

#define MEM_DIM  100
#define TIME_DIM 100
#define EDGE_DIM 172
#define HIDDEN   128
#define IN_DIM   472          // 100 + 100 + 100 + 172
#define K_PAD    480          // 15 * 32, zero-padded rows 472..479
#define BM       64           // edges per block
#define BK       32           // K chunk
#define XP       (BM + 1)     // LDS pitch 65: conflict-free stride-65 writes

__global__ __launch_bounds__(256)
void tgn_fused(const int* __restrict__ src, const int* __restrict__ dst,
               const float* __restrict__ t, const float* __restrict__ edge_attr,
               const float* __restrict__ memory, const float* __restrict__ last_update,
               const float* __restrict__ time_w, const float* __restrict__ time_b,
               const float* __restrict__ w1, const float* __restrict__ b1,
               const float* __restrict__ w2, const float* __restrict__ b2,
               float* __restrict__ out, int E)
{
    __shared__ float Xs[K_PAD * XP];     // 124800 B, X-tile transposed: Xs[k][m]
    __shared__ float W1s[BK * HIDDEN];   // 16384 B
    __shared__ int   s_src[BM];
    __shared__ int   s_dst[BM];
    __shared__ float s_dt[BM];

    const int tid = threadIdx.x;
    const int e0  = blockIdx.x * BM;

    // ---- per-edge scalars ----
    if (tid < BM) {
        int e = e0 + tid; if (e >= E) e = E - 1;   // clamp (dup work, guarded store)
        int s = src[e];
        s_src[tid] = s;
        s_dst[tid] = dst[e];
        s_dt[tid]  = t[e] - last_update[s];
    }
    __syncthreads();

    // ---- phase 0: build X tile in LDS (k-major, pitch 65) ----
    // src memory rows -> k in [0,100)
    for (int idx = tid; idx < BM * MEM_DIM; idx += 256) {
        int m = idx / MEM_DIM, c = idx - m * MEM_DIM;
        Xs[c * XP + m] = memory[(long)s_src[m] * MEM_DIM + c];
    }
    // dst memory rows -> k in [100,200)
    for (int idx = tid; idx < BM * MEM_DIM; idx += 256) {
        int m = idx / MEM_DIM, c = idx - m * MEM_DIM;
        Xs[(MEM_DIM + c) * XP + m] = memory[(long)s_dst[m] * MEM_DIM + c];
    }
    // time encoding -> k in [200,300)
    for (int idx = tid; idx < BM * TIME_DIM; idx += 256) {
        int m = idx / TIME_DIM, c = idx - m * TIME_DIM;
        float a = s_dt[m] * time_w[c] + time_b[c];
        Xs[(2 * MEM_DIM + c) * XP + m] = cosf(a);
    }
    // edge_attr -> k in [300,472)
    for (int idx = tid; idx < BM * EDGE_DIM; idx += 256) {
        int m = idx / EDGE_DIM, c = idx - m * EDGE_DIM;
        int e = e0 + m; if (e >= E) e = E - 1;
        Xs[(300 + c) * XP + m] = edge_attr[(long)e * EDGE_DIM + c];
    }
    // zero-pad rows [472,480)
    for (int idx = tid; idx < (K_PAD - IN_DIM) * BM; idx += 256) {
        int r = idx / BM, m = idx - r * BM;
        Xs[(IN_DIM + r) * XP + m] = 0.0f;
    }

    // ---- phase 1: register-blocked GEMM, 4m x 8n per thread ----
    const int tx = tid & 15;        // 16 n-groups of 8 cols
    const int ty = tid >> 4;        // 16 m-groups of 4 rows
    const int m0 = ty * 4, n0 = tx * 8;

    float acc[4][8];
    #pragma unroll
    for (int i = 0; i < 4; ++i)
        #pragma unroll
        for (int j = 0; j < 8; ++j) acc[i][j] = 0.0f;

    for (int k0 = 0; k0 < K_PAD; k0 += BK) {
        __syncthreads();
        // stage W1 chunk (float4, OOB-guarded: rows >= 472 are never read anyway
        // since Xs rows are zero, but poison could be NaN and NaN*0 = NaN)
        for (int i = tid; i < BK * HIDDEN / 4; i += 256) {
            int g = k0 * HIDDEN + i * 4;
            float4 v;
            if (g < IN_DIM * HIDDEN) v = *(const float4*)(w1 + g);
            else                     v = make_float4(0.f, 0.f, 0.f, 0.f);
            *(float4*)(W1s + i * 4) = v;
        }
        __syncthreads();

        #pragma unroll
        for (int k = 0; k < BK; ++k) {
            const float* xr = &Xs[(k0 + k) * XP + m0];
            float a0 = xr[0], a1 = xr[1], a2 = xr[2], a3 = xr[3];
            const float* wr = &W1s[k * HIDDEN + n0];
            float b[8];
            #pragma unroll
            for (int j = 0; j < 8; ++j) b[j] = wr[j];
            #pragma unroll
            for (int j = 0; j < 8; ++j) {
                acc[0][j] += a0 * b[j];
                acc[1][j] += a1 * b[j];
                acc[2][j] += a2 * b[j];
                acc[3][j] += a3 * b[j];
            }
        }
    }

    // ---- epilogue: bias + relu + dot(w2) + 16-lane reduction ----
    float part[4] = {0.f, 0.f, 0.f, 0.f};
    #pragma unroll
    for (int j = 0; j < 8; ++j) {
        float b1j = b1[n0 + j];
        float w2j = w2[n0 + j];
        #pragma unroll
        for (int i = 0; i < 4; ++i) {
            float h = acc[i][j] + b1j;
            h = h > 0.f ? h : 0.f;
            part[i] += h * w2j;
        }
    }
    const float b2v = b2[0];
    #pragma unroll
    for (int i = 0; i < 4; ++i) {
        float p = part[i];
        p += __shfl_xor(p, 1, 64);
        p += __shfl_xor(p, 2, 64);
        p += __shfl_xor(p, 4, 64);
        p += __shfl_xor(p, 8, 64);
        if (tx == 0) {
            int e = e0 + m0 + i;
            if (e < E) out[e] = p + b2v;
        }
    }
}

extern "C" void kernel_launch(void* const* d_in, const int* in_sizes, int n_in,
                              void* d_out, int out_size, void* d_ws, size_t ws_size,
                              hipStream_t stream) {
    const int*   src = (const int*)d_in[0];
    const int*   dst = (const int*)d_in[1];
    const float* t   = (const float*)d_in[2];
    const float* ea  = (const float*)d_in[3];
    const float* mem = (const float*)d_in[4];
    const float* lu  = (const float*)d_in[5];
    const float* tw  = (const float*)d_in[6];
    const float* tb  = (const float*)d_in[7];
    const float* w1  = (const float*)d_in[8];
    const float* b1  = (const float*)d_in[9];
    const float* w2  = (const float*)d_in[10];
    const float* b2  = (const float*)d_in[11];
    float* out = (float*)d_out;
    const int E = in_sizes[0];

    int grid = (E + BM - 1) / BM;
    tgn_fused<<<grid, 256, 0, stream>>>(src, dst, t, ea, mem, lu, tw, tb,
                                        w1, b1, w2, b2, out, E);
}

// Round 2
// 1610.127 us; speedup vs baseline: 1.7396x; 1.7396x over previous
//
#include <hip/hip_runtime.h>
#include <math.h>

#define MEM_DIM  100
#define TIME_DIM 100
#define EDGE_DIM 172
#define HIDDEN   128
#define IN_DIM   472          // 100 + 100 + 100 + 172
#define K_PAD    480          // 15 * 32, rows 472..479 are zero
#define BM       64           // edges per block
#define BK       32           // K chunk staged per iteration
#define XP       (BM + 1)     // pitch 65: Xs write banks (c+m)%32 -> 2-way = free

// LDS: Xs 32*65*4 = 8320 B, W1s 32*128*4 = 16384 B, + ~800 B scalars ≈ 25.5 KB
// -> LDS allows 6 blocks/CU; VGPR cap 128 via __launch_bounds__(256,4) -> 4 blocks/CU (50%).

__global__ __launch_bounds__(256, 4)
void tgn_fused(const int* __restrict__ src, const int* __restrict__ dst,
               const float* __restrict__ t, const float* __restrict__ edge_attr,
               const float* __restrict__ memory, const float* __restrict__ last_update,
               const float* __restrict__ time_w, const float* __restrict__ time_b,
               const float* __restrict__ w1, const float* __restrict__ b1,
               const float* __restrict__ w2, const float* __restrict__ b2,
               float* __restrict__ out, int E)
{
    __shared__ float Xs[BK * XP];        // X chunk, transposed: Xs[c][m]
    __shared__ float W1s[BK * HIDDEN];   // W1 chunk
    __shared__ int   s_src[BM];
    __shared__ int   s_dst[BM];
    __shared__ float s_dt[BM];

    const int tid = threadIdx.x;
    const int e0  = blockIdx.x * BM;

    // ---- per-edge scalars ----
    if (tid < BM) {
        int e = e0 + tid; if (e >= E) e = E - 1;   // clamp (dup work, guarded store)
        int s = src[e];
        s_src[tid] = s;
        s_dst[tid] = dst[e];
        s_dt[tid]  = t[e] - last_update[s];
    }
    __syncthreads();

    // ---- thread tile: 4m x (4+4)n, columns tx*4 and tx*4+64 (bank-conflict-free) ----
    const int tx = tid & 15;
    const int ty = tid >> 4;
    const int m0 = ty * 4;
    const int n0 = tx * 4;

    float acc[4][8];
    #pragma unroll
    for (int i = 0; i < 4; ++i)
        #pragma unroll
        for (int j = 0; j < 8; ++j) acc[i][j] = 0.0f;

    for (int k0 = 0; k0 < K_PAD; k0 += BK) {
        // ---- stage X chunk: lanes read k-contiguous (coalesced), write transposed ----
        // idx: c = k-offset fastest -> lanes 0..31 read cols k0..k0+31 of row m (128 B)
        for (int idx = tid; idx < BK * BM; idx += 256) {
            int m = idx >> 5;          // 0..63
            int c = idx & 31;          // 0..31
            int k = k0 + c;
            float v;
            if (k < MEM_DIM) {
                v = memory[(long)s_src[m] * MEM_DIM + k];
            } else if (k < 2 * MEM_DIM) {
                v = memory[(long)s_dst[m] * MEM_DIM + (k - MEM_DIM)];
            } else if (k < 2 * MEM_DIM + TIME_DIM) {
                int c2 = k - 2 * MEM_DIM;
                v = cosf(s_dt[m] * time_w[c2] + time_b[c2]);
            } else if (k < IN_DIM) {
                int e = e0 + m; if (e >= E) e = E - 1;
                v = edge_attr[(long)e * EDGE_DIM + (k - 300)];
            } else {
                v = 0.0f;
            }
            Xs[c * XP + m] = v;
        }
        // ---- stage W1 chunk (float4; zero-fill padded rows so 0xAA poison can't NaN) ----
        for (int i = tid; i < BK * HIDDEN / 4; i += 256) {
            int g4 = k0 * HIDDEN + i * 4;
            float4 v;
            if (g4 < IN_DIM * HIDDEN) v = *(const float4*)(w1 + g4);
            else                      v = make_float4(0.f, 0.f, 0.f, 0.f);
            *(float4*)(W1s + i * 4) = v;
        }
        __syncthreads();

        #pragma unroll 8
        for (int k = 0; k < BK; ++k) {
            float4 av = *(const float4*)&Xs[k * XP + m0];              // 16-lane broadcast
            float4 bl = *(const float4*)&W1s[k * HIDDEN + n0];         // banks tx*4%32, 2-way
            float4 bh = *(const float4*)&W1s[k * HIDDEN + n0 + 64];
            float a[4] = {av.x, av.y, av.z, av.w};
            float b[8] = {bl.x, bl.y, bl.z, bl.w, bh.x, bh.y, bh.z, bh.w};
            #pragma unroll
            for (int j = 0; j < 8; ++j)
                #pragma unroll
                for (int i = 0; i < 4; ++i)
                    acc[i][j] += a[i] * b[j];
        }
        __syncthreads();
    }

    // ---- epilogue: bias + relu + dot(w2), reduce across the 16 tx lanes ----
    float part[4] = {0.f, 0.f, 0.f, 0.f};
    #pragma unroll
    for (int j = 0; j < 8; ++j) {
        int col = (j < 4) ? (n0 + j) : (n0 + 64 + j - 4);
        float b1j = b1[col];
        float w2j = w2[col];
        #pragma unroll
        for (int i = 0; i < 4; ++i) {
            float h = acc[i][j] + b1j;
            h = h > 0.f ? h : 0.f;
            part[i] += h * w2j;
        }
    }
    const float b2v = b2[0];
    #pragma unroll
    for (int i = 0; i < 4; ++i) {
        float p = part[i];
        p += __shfl_xor(p, 1, 64);
        p += __shfl_xor(p, 2, 64);
        p += __shfl_xor(p, 4, 64);
        p += __shfl_xor(p, 8, 64);
        if (tx == 0) {
            int e = e0 + m0 + i;
            if (e < E) out[e] = p + b2v;
        }
    }
}

extern "C" void kernel_launch(void* const* d_in, const int* in_sizes, int n_in,
                              void* d_out, int out_size, void* d_ws, size_t ws_size,
                              hipStream_t stream) {
    const int*   src = (const int*)d_in[0];
    const int*   dst = (const int*)d_in[1];
    const float* t   = (const float*)d_in[2];
    const float* ea  = (const float*)d_in[3];
    const float* mem = (const float*)d_in[4];
    const float* lu  = (const float*)d_in[5];
    const float* tw  = (const float*)d_in[6];
    const float* tb  = (const float*)d_in[7];
    const float* w1  = (const float*)d_in[8];
    const float* b1  = (const float*)d_in[9];
    const float* w2  = (const float*)d_in[10];
    const float* b2  = (const float*)d_in[11];
    float* out = (float*)d_out;
    const int E = in_sizes[0];

    int grid = (E + BM - 1) / BM;
    tgn_fused<<<grid, 256, 0, stream>>>(src, dst, t, ea, mem, lu, tw, tb,
                                        w1, b1, w2, b2, out, E);
}

// Round 3
// 820.100 us; speedup vs baseline: 3.4154x; 1.9633x over previous
//
#include <hip/hip_runtime.h>
#include <hip/hip_bf16.h>
#include <math.h>

#define MEM_DIM  100
#define TIME_DIM 100
#define EDGE_DIM 172
#define HIDDEN   128
#define IN_DIM   472
#define K_PAD    480          // 15 chunks of 32; rows 472..479 zero
#define NCHUNK   15
#define BM       64           // edges per block (4 waves x 16)
#define BK       32           // one MFMA K per chunk

typedef __attribute__((ext_vector_type(8))) short bf16x8;
typedef __attribute__((ext_vector_type(4))) float floatx4;

typedef const __attribute__((address_space(1))) unsigned int* gp_t;
typedef __attribute__((address_space(3))) unsigned int* lp_t;

// ---------------------------------------------------------------------------
// Prep: permute W1 (fp32, [IN_DIM][HIDDEN]) into bf16 MFMA-B fragment order:
//   value = W1[k][n], k = c*32 + quad*8 + j, n = t*16 + r
//   w1p element offset = ((c*8 + t)*64 + quad*16 + r)*8 + j
// Rows k >= IN_DIM are zeroed (d_ws is 0xAA-poisoned before every call).
// ---------------------------------------------------------------------------
__global__ void prep_w1(const float* __restrict__ w1, __hip_bfloat16* __restrict__ w1p) {
    int idx = blockIdx.x * 256 + threadIdx.x;          // over K_PAD*HIDDEN
    if (idx >= K_PAD * HIDDEN) return;
    int k = idx >> 7;                                  // coalesced read: n fastest
    int n = idx & 127;
    float v = (k < IN_DIM) ? w1[k * HIDDEN + n] : 0.0f;
    int c = k >> 5, kl = k & 31, quad = kl >> 3, j = kl & 7;
    int t = n >> 4, r = n & 15;
    int off = ((c * 8 + t) * 64 + quad * 16 + r) * 8 + j;
    w1p[off] = __float2bfloat16(v);
}

// ---------------------------------------------------------------------------
// Fused TGN decoder: gather + time-encode + [E,472]x[472,128] MFMA + ReLU + w2 dot
// ---------------------------------------------------------------------------
__global__ __launch_bounds__(256, 6)
void tgn_mfma(const int* __restrict__ src, const int* __restrict__ dst,
              const float* __restrict__ t, const float* __restrict__ edge_attr,
              const float* __restrict__ memory, const float* __restrict__ last_update,
              const float* __restrict__ time_w, const float* __restrict__ time_b,
              const __hip_bfloat16* __restrict__ w1p, const float* __restrict__ b1,
              const float* __restrict__ w2, const float* __restrict__ b2,
              float* __restrict__ out, int E)
{
    __shared__ __hip_bfloat16 Xs[BM * BK];       // 4 KB, A-frag order: (g*64+lane)*8+j
    __shared__ __hip_bfloat16 W1s[8 * 64 * 8];   // 8 KB, B-frag order: (t*64+lane)*8+j
    __shared__ int   s_src[BM];
    __shared__ int   s_dst[BM];
    __shared__ float s_dt[BM];
    __shared__ float s_tw[TIME_DIM], s_tb[TIME_DIM];
    __shared__ float s_b1[HIDDEN], s_w2[HIDDEN];

    const int tid  = threadIdx.x;
    const int e0   = blockIdx.x * BM;
    const int g    = tid >> 6;          // wave id: edges [g*16, g*16+16)
    const int lane = tid & 63;
    const int quad = (tid >> 4) & 3;
    const int r    = tid & 15;

    if (tid < BM) {
        int e = e0 + tid; if (e >= E) e = E - 1;   // clamp; store is guarded
        int s = src[e];
        s_src[tid] = s;
        s_dst[tid] = dst[e];
        s_dt[tid]  = t[e] - last_update[s];
    }
    if (tid < HIDDEN) { s_b1[tid] = b1[tid]; s_w2[tid] = w2[tid]; }
    if (tid < TIME_DIM) { s_tw[tid] = time_w[tid]; s_tb[tid] = time_b[tid]; }
    __syncthreads();

    // per-thread staging row pointers (thread owns edge m, k-span [c*32+quad*8, +8))
    const int m = g * 16 + r;
    const float* srcrow = memory + (long)s_src[m] * MEM_DIM;
    const float* dstrow = memory + (long)s_dst[m] * MEM_DIM;
    int em = e0 + m; if (em >= E) em = E - 1;
    const float* earow = edge_attr + (long)em * EDGE_DIM;
    const float dt = s_dt[m];

    floatx4 acc[8];
    #pragma unroll
    for (int i = 0; i < 8; ++i) acc[i] = (floatx4){0.f, 0.f, 0.f, 0.f};

    for (int c = 0; c < NCHUNK; ++c) {
        // ---- stage W1 chunk: pure 16 B async copies (frag order already) ----
        {
            const __hip_bfloat16* w1c = w1p + c * (8 * 64 * 8);
            // wave g copies bytes [g*2048, g*2048+2048): 2 calls x (64 lanes x 16 B)
            const __hip_bfloat16* gsrc = w1c + g * 1024 + lane * 8;
            __hip_bfloat16* ldst = W1s + g * 1024;
            __builtin_amdgcn_global_load_lds((gp_t)(const void*)gsrc,
                                             (lp_t)(void*)ldst, 16, 0, 0);
            __builtin_amdgcn_global_load_lds((gp_t)(const void*)(gsrc + 512),
                                             (lp_t)(void*)(ldst + 512), 16, 0, 0);
        }
        // ---- stage X chunk in A-frag order: thread writes 8 consecutive k ----
        {
            const int kb = c * BK + quad * 8;
            float v[8];
            if (kb + 7 < MEM_DIM) {
                float4 lo = *(const float4*)(srcrow + kb);
                float4 hi = *(const float4*)(srcrow + kb + 4);
                v[0]=lo.x; v[1]=lo.y; v[2]=lo.z; v[3]=lo.w;
                v[4]=hi.x; v[5]=hi.y; v[6]=hi.z; v[7]=hi.w;
            } else if (kb >= MEM_DIM && kb + 7 < 2 * MEM_DIM) {
                float4 lo = *(const float4*)(dstrow + kb - MEM_DIM);
                float4 hi = *(const float4*)(dstrow + kb - MEM_DIM + 4);
                v[0]=lo.x; v[1]=lo.y; v[2]=lo.z; v[3]=lo.w;
                v[4]=hi.x; v[5]=hi.y; v[6]=hi.z; v[7]=hi.w;
            } else if (kb >= 200 && kb + 7 < 300) {
                int c0 = kb - 200;
                #pragma unroll
                for (int j = 0; j < 8; ++j)
                    v[j] = cosf(dt * s_tw[c0 + j] + s_tb[c0 + j]);
            } else if (kb >= 300 && kb + 7 < IN_DIM) {
                float4 lo = *(const float4*)(earow + kb - 300);
                float4 hi = *(const float4*)(earow + kb - 300 + 4);
                v[0]=lo.x; v[1]=lo.y; v[2]=lo.z; v[3]=lo.w;
                v[4]=hi.x; v[5]=hi.y; v[6]=hi.z; v[7]=hi.w;
            } else {
                #pragma unroll
                for (int j = 0; j < 8; ++j) {
                    int k = kb + j;
                    float x;
                    if (k < MEM_DIM)          x = srcrow[k];
                    else if (k < 2 * MEM_DIM) x = dstrow[k - MEM_DIM];
                    else if (k < 300)         x = cosf(dt * s_tw[k - 200] + s_tb[k - 200]);
                    else if (k < IN_DIM)      x = earow[k - 300];
                    else                      x = 0.0f;
                    v[j] = x;
                }
            }
            short fr[8];
            #pragma unroll
            for (int j = 0; j < 8; ++j)
                fr[j] = (short)__bfloat16_as_ushort(__float2bfloat16(v[j]));
            ((bf16x8*)Xs)[tid] = *(bf16x8*)fr;
        }
        __syncthreads();   // drains vmcnt (global_load_lds) + lgkm

        // ---- 8 MFMAs: wave g's 16 edges x all 128 cols, K=32 ----
        bf16x8 afrag = ((bf16x8*)Xs)[g * 64 + lane];
        #pragma unroll
        for (int tnum = 0; tnum < 8; ++tnum) {
            bf16x8 bfrag = ((bf16x8*)W1s)[tnum * 64 + lane];
            acc[tnum] = __builtin_amdgcn_mfma_f32_16x16x32_bf16(afrag, bfrag, acc[tnum], 0, 0, 0);
        }
        __syncthreads();
    }

    // ---- epilogue: h = relu(acc + b1); out = h . w2 + b2 (all fp32) ----
    // C/D layout: n = tnum*16 + (lane&15), m_local = quad*4 + reg
    float part[4] = {0.f, 0.f, 0.f, 0.f};
    #pragma unroll
    for (int tnum = 0; tnum < 8; ++tnum) {
        int n = tnum * 16 + r;
        float b1n = s_b1[n];
        float w2n = s_w2[n];
        #pragma unroll
        for (int reg = 0; reg < 4; ++reg) {
            float h = acc[tnum][reg] + b1n;
            h = h > 0.f ? h : 0.f;
            part[reg] += h * w2n;
        }
    }
    const float b2v = b2[0];
    #pragma unroll
    for (int reg = 0; reg < 4; ++reg) {
        float p = part[reg];
        p += __shfl_xor(p, 1, 64);
        p += __shfl_xor(p, 2, 64);
        p += __shfl_xor(p, 4, 64);
        p += __shfl_xor(p, 8, 64);
        if (r == 0) {
            int e = e0 + g * 16 + quad * 4 + reg;
            if (e < E) out[e] = p + b2v;
        }
    }
}

extern "C" void kernel_launch(void* const* d_in, const int* in_sizes, int n_in,
                              void* d_out, int out_size, void* d_ws, size_t ws_size,
                              hipStream_t stream) {
    const int*   src = (const int*)d_in[0];
    const int*   dst = (const int*)d_in[1];
    const float* t   = (const float*)d_in[2];
    const float* ea  = (const float*)d_in[3];
    const float* mem = (const float*)d_in[4];
    const float* lu  = (const float*)d_in[5];
    const float* tw  = (const float*)d_in[6];
    const float* tb  = (const float*)d_in[7];
    const float* w1  = (const float*)d_in[8];
    const float* b1  = (const float*)d_in[9];
    const float* w2  = (const float*)d_in[10];
    const float* b2  = (const float*)d_in[11];
    float* out = (float*)d_out;
    const int E = in_sizes[0];

    __hip_bfloat16* w1p = (__hip_bfloat16*)d_ws;   // 480*128*2 = 122880 B

    prep_w1<<<(K_PAD * HIDDEN + 255) / 256, 256, 0, stream>>>(w1, w1p);

    int grid = (E + BM - 1) / BM;
    tgn_mfma<<<grid, 256, 0, stream>>>(src, dst, t, ea, mem, lu, tw, tb,
                                       w1p, b1, w2, b2, out, E);
}